// Round 3
// baseline (94.437 us; speedup 1.0000x reference)
//
#include <hip/hip_runtime.h>
#include <hip/hip_bf16.h>

// Problem constants (reference: B,E,P,L,D = 16,2048,16384,5,64)
#define B 16
#define E 2048
#define P 16384
#define L 5
#define D 64
#define EPS 1e-9f

// Fused single-launch kernel.
// Grid: 256 blocks x 256 threads. Block -> (b = blk & 15, chunk g = blk >> 4).
// Since blocks of batch b are blockIdx ≡ b (mod 16), they map to one XCD
// (round-robin %8), so emb[b] (512 KB) is HBM-fetched once and L2-served to
// the other 15 blocks.
// Phase A: block computes proj[b][e][l] = dot(emb[b,e,:], ev[l,:]) for all
//          2048 edges into 40 KB LDS (redundant per block, ~1-2 us, pk-fma).
// Phase B: gather 1024 paths from LDS, normalize, write out.
__global__ __launch_bounds__(256) void edge_fused_kernel(
    const float* __restrict__ emb, const int* __restrict__ paths,
    const float* __restrict__ ev, float* __restrict__ out) {
    __shared__ float sproj[E * L];  // 40 KB
    __shared__ float sev[L * D];    // 1.25 KB

    const int t = threadIdx.x;
    const int b = blockIdx.x & 15;
    const int g = blockIdx.x >> 4;

    // stage ev once (coalesced; 320 floats)
    for (int i = t; i < L * D; i += 256) sev[i] = ev[i];
    __syncthreads();

    // ---- Phase A: projection into LDS ----
    // Each thread owns 8 rows: e = t + r*256. Accumulate in float2 pairs so
    // the compiler can pack into v_pk_fma_f32.
    {
        const float4* __restrict__ rb =
            (const float4*)(emb + ((size_t)b * E + t) * D);
        const float4* __restrict__ w4 = (const float4*)sev;

        float accx[8][L], accy[8][L];
#pragma unroll
        for (int r = 0; r < 8; ++r)
#pragma unroll
            for (int l = 0; l < L; ++l) { accx[r][l] = 0.f; accy[r][l] = 0.f; }

#pragma unroll
        for (int c = 0; c < D / 4; ++c) {
            float4 w[L];
#pragma unroll
            for (int l = 0; l < L; ++l) w[l] = w4[l * (D / 4) + c];  // LDS broadcast
#pragma unroll
            for (int r = 0; r < 8; ++r) {
                float4 v = rb[r * (256 * D / 4) + c];  // row stride 256 rows
#pragma unroll
                for (int l = 0; l < L; ++l) {
                    accx[r][l] = fmaf(v.x, w[l].x, accx[r][l]);
                    accy[r][l] = fmaf(v.y, w[l].y, accy[r][l]);
                    accx[r][l] = fmaf(v.z, w[l].z, accx[r][l]);
                    accy[r][l] = fmaf(v.w, w[l].w, accy[r][l]);
                }
            }
        }
#pragma unroll
        for (int r = 0; r < 8; ++r) {
            int e = t + r * 256;
#pragma unroll
            for (int l = 0; l < L; ++l)
                sproj[e * L + l] = accx[r][l] + accy[r][l];
        }
    }
    __syncthreads();

    // ---- Phase B: gather + normalize ----
    const int pbase = g * (P / 16);  // 1024 paths per block
#pragma unroll
    for (int k = 0; k < 4; ++k) {
        int p = pbase + k * 256 + t;
        const int* __restrict__ pp = paths + ((size_t)b * P + p) * L;
        float sum = 0.f;
        int cnt = 0;
#pragma unroll
        for (int l = 0; l < L; ++l) {
            int e = pp[l];
            bool valid = (e >= 0);
            int ec = valid ? e : 0;
            float v = sproj[ec * L + l];
            sum += valid ? v : 0.f;
            cnt += valid ? 1 : 0;
        }
        out[(size_t)b * P + p] = sum / ((float)cnt + EPS);
    }
}

extern "C" void kernel_launch(void* const* d_in, const int* in_sizes, int n_in,
                              void* d_out, int out_size, void* d_ws, size_t ws_size,
                              hipStream_t stream) {
    const float* emb   = (const float*)d_in[0];  // (B,E,D) f32
    const int*   paths = (const int*)d_in[1];    // (B,P,L) int32
    const float* ev    = (const float*)d_in[2];  // (L,D) f32
    float* out = (float*)d_out;                  // (B,P) f32

    edge_fused_kernel<<<16 * B, 256, 0, stream>>>(emb, paths, ev, out);
}

// Round 4
// 69.740 us; speedup vs baseline: 1.3541x; 1.3541x over previous
//
#include <hip/hip_runtime.h>
#include <hip/hip_bf16.h>

// Problem constants (reference: B,E,P,L,D = 16,2048,16384,5,64)
#define B 16
#define E 2048
#define P 16384
#define L 5
#define D 64
#define EPS 1e-9f

// Kernel 1: proj[(b*E+e)*L + l] = dot(emb[b,e,:], ev[l,:])
// 4 lanes per row: lane owns 16 consecutive floats (64 B) -> per-instruction
// lane addresses are contiguous 64 B segments (fully coalesced dwordx4).
// Quad shuffle-reduce combines the 4 partial dots.
// Grid: 512 blocks x 256 threads = 131072 threads = 4 * 32768 rows (8 waves/CU).
__global__ __launch_bounds__(256) void edge_proj_kernel(
    const float* __restrict__ emb, const float* __restrict__ ev,
    float* __restrict__ proj) {
    int gid   = blockIdx.x * 256 + threadIdx.x;
    int row   = gid >> 2;        // (b,e) flat, 0..B*E
    int qlane = gid & 3;         // which 16-float chunk of D

    // weights: 5 x 4 float4, tiny L1/L2-resident buffer (no LDS, no barrier)
    const float4* __restrict__ w4 = (const float4*)ev;
    float4 w[L][4];
#pragma unroll
    for (int l = 0; l < L; ++l)
#pragma unroll
        for (int c = 0; c < 4; ++c) w[l][c] = w4[l * 16 + qlane * 4 + c];

    const float4* __restrict__ src =
        (const float4*)(emb + (size_t)row * D + qlane * 16);
    float4 v[4];
#pragma unroll
    for (int c = 0; c < 4; ++c) v[c] = src[c];

    float acc[L];
#pragma unroll
    for (int l = 0; l < L; ++l) {
        float a = 0.f;
#pragma unroll
        for (int c = 0; c < 4; ++c)
            a += v[c].x * w[l][c].x + v[c].y * w[l][c].y +
                 v[c].z * w[l][c].z + v[c].w * w[l][c].w;
        // quad reduce (lanes 4r..4r+3 in same wave)
        a += __shfl_xor(a, 1);
        a += __shfl_xor(a, 2);
        acc[l] = a;
    }

    if (qlane == 0) {
        float* p = proj + (size_t)row * L;
#pragma unroll
        for (int l = 0; l < L; ++l) p[l] = acc[l];
    }
}

// Kernel 2: stage proj[b] (40 KB) into LDS (coalesced float4), gather from LDS.
// Grid: 1024 blocks x 256 threads, 1 path/thread; 4 blocks/CU (LDS-limited),
// 16 waves/CU.
__global__ __launch_bounds__(256) void edge_gather_kernel(
    const int* __restrict__ paths, const float* __restrict__ proj,
    float* __restrict__ out) {
    __shared__ float sproj[E * L];  // 40 KB
    const int t = threadIdx.x;
    const int b = blockIdx.x >> 6;  // 64 blocks per batch
    const int g = blockIdx.x & 63;

    const float4* __restrict__ src = (const float4*)(proj + (size_t)b * E * L);
    float4* dst = (float4*)sproj;
#pragma unroll
    for (int i = 0; i < (E * L) / 4 / 256; ++i)  // 10 float4 per thread
        dst[t + i * 256] = src[t + i * 256];
    __syncthreads();

    int p = g * 256 + t;
    const int* __restrict__ pp = paths + ((size_t)b * P + p) * L;
    float sum = 0.f;
    int cnt = 0;
#pragma unroll
    for (int l = 0; l < L; ++l) {
        int e = pp[l];
        bool valid = (e >= 0);
        int ec = valid ? e : 0;
        float v = sproj[ec * L + l];
        sum += valid ? v : 0.f;
        cnt += valid ? 1 : 0;
    }
    out[(size_t)b * P + p] = sum / ((float)cnt + EPS);
}

extern "C" void kernel_launch(void* const* d_in, const int* in_sizes, int n_in,
                              void* d_out, int out_size, void* d_ws, size_t ws_size,
                              hipStream_t stream) {
    const float* emb   = (const float*)d_in[0];  // (B,E,D) f32
    const int*   paths = (const int*)d_in[1];    // (B,P,L) int32
    const float* ev    = (const float*)d_in[2];  // (L,D) f32
    float* out  = (float*)d_out;                 // (B,P) f32
    float* proj = (float*)d_ws;                  // (B,E,L) f32 = 640 KB scratch

    edge_proj_kernel<<<(4 * B * E) / 256, 256, 0, stream>>>(emb, ev, proj);
    edge_gather_kernel<<<64 * B, 256, 0, stream>>>(paths, proj, out);
}